// Round 5
// baseline (508.788 us; speedup 1.0000x reference)
//
#include <hip/hip_runtime.h>

#define NNODES 100000
#define NEDGES 1000000
#define DIM 64
#define NGRAPHS 128
#define NLAYERS 3
#define BN_EPS 1e-5f

#define BINSZ 16
#define NBINS 6250          // 16 nodes per bin, 6250*16 == NNODES exactly
#define GBLK 256            // blocks for count/scatter passes
#define ECHUNK 3907         // ceil(NEDGES/GBLK)

// workspace layout (4-byte element offsets)
#define OFF_EDGES   0            // int2[NEDGES] = 2,000,000 ints
#define OFF_BINBASE 2000000      // int[NBINS+1]
#define OFF_AGG     2006272      // float[NNODES*64]
#define OFF_Y       8406272      // float[NNODES*64]
// counts/offsets/binTotal overlay the (not yet used) Y region during preprocessing
#define OFF_COUNTS  8406272      // int[NBINS*GBLK] = 1,600,000
#define OFF_OFFS    10006272     // int[NBINS*GBLK] = 1,600,000
#define OFF_BTOT    11606272     // int[NBINS]
// stats region
#define OFF_SCALE   14806272     // float[NLAYERS*64]
#define OFF_SHIFT   14806464     // float[NLAYERS*64]
#define OFF_GSUM    14806656     // float[NGRAPHS*64]
#define OFF_PS      14814848     // float[NGRAPHS*64]
#define OFF_PQ      14823040     // float[NGRAPHS*64]
#define OFF_END     14831232     // int[NGRAPHS]

// ---- preprocessing: bin 1M edges by dst/16 with zero global atomics ----

__global__ __launch_bounds__(1024) void count_kernel(const int* __restrict__ ei,
                                                     int* __restrict__ counts) {
    __shared__ int hist[NBINS];
    const int tid = threadIdx.x, blk = blockIdx.x;
    for (int i = tid; i < NBINS; i += 1024) hist[i] = 0;
    __syncthreads();
    const int e0 = blk * ECHUNK, e1 = min(NEDGES, e0 + ECHUNK);
    for (int e = e0 + tid; e < e1; e += 1024)
        atomicAdd(&hist[ei[NEDGES + e] / BINSZ], 1);
    __syncthreads();
    for (int bin = tid; bin < NBINS; bin += 1024)
        counts[bin * GBLK + blk] = hist[bin];
}

// one wave per bin: exclusive scan of the GBLK per-block counts + bin total
__global__ __launch_bounds__(256) void s1_kernel(const int* __restrict__ counts,
                                                 int* __restrict__ offs,
                                                 int* __restrict__ btot) {
    const int bin = blockIdx.x * 4 + (threadIdx.x >> 6);
    const int lane = threadIdx.x & 63;
    if (bin >= NBINS) return;
    int carry = 0;
    for (int q = 0; q < GBLK; q += 64) {
        const int v = counts[bin * GBLK + q + lane];
        int s = v;
        for (int off = 1; off < 64; off <<= 1) {
            int t = __shfl_up(s, off);
            if (lane >= off) s += t;
        }
        offs[bin * GBLK + q + lane] = carry + s - v;
        carry += __shfl(s, 63);
    }
    if (lane == 0) btot[bin] = carry;
}

// single-block exclusive scan over NBINS bin totals -> binBase (+ sentinel)
__global__ __launch_bounds__(1024) void s2_kernel(const int* __restrict__ btot,
                                                  int* __restrict__ binBase) {
    __shared__ int s[1024];
    const int t = threadIdx.x;
    int running = 0;
    for (int base = 0; base < NBINS; base += 1024) {
        const int i = base + t;
        const int v = (i < NBINS) ? btot[i] : 0;
        __syncthreads();
        s[t] = v;
        __syncthreads();
        for (int off = 1; off < 1024; off <<= 1) {
            int x = (t >= off) ? s[t - off] : 0;
            __syncthreads();
            s[t] += x;
            __syncthreads();
        }
        if (i < NBINS) binBase[i] = running + s[t] - v;
        running += s[1023];
    }
    if (t == 0) binBase[NBINS] = running;
}

__global__ __launch_bounds__(1024) void scatter_kernel(const int* __restrict__ ei,
                                                       const float* __restrict__ ea,
                                                       const int* __restrict__ binBase,
                                                       const int* __restrict__ offs,
                                                       int2* __restrict__ edges) {
    __shared__ int cur[NBINS];
    const int tid = threadIdx.x, blk = blockIdx.x;
    for (int i = tid; i < NBINS; i += 1024)
        cur[i] = binBase[i] + offs[i * GBLK + blk];
    __syncthreads();
    const int e0 = blk * ECHUNK, e1 = min(NEDGES, e0 + ECHUNK);
    for (int e = e0 + tid; e < e1; e += 1024) {
        const int dst = ei[NEDGES + e];
        const int src = ei[e];
        const float w = ea[e];
        const int pos = atomicAdd(&cur[dst / BINSZ], 1);   // LDS atomic
        edges[pos] = make_int2((src << 4) | (dst & (BINSZ - 1)), __float_as_int(w));
    }
}

// per-graph end offsets from the sorted batch vector (no atomics)
__global__ __launch_bounds__(1024) void bounds_kernel(const int* __restrict__ batch,
                                                      int* __restrict__ endv) {
    const int i = blockIdx.x * 1024 + threadIdx.x;
    if (i >= NNODES) return;
    const int b0 = batch[i];
    const int b1 = (i + 1 < NNODES) ? batch[i + 1] : NGRAPHS;
    for (int g = b0; g < b1; ++g) endv[g] = i + 1;
    if (i == 0)
        for (int g = 0; g < b0; ++g) endv[g] = 0;
}

// ---- aggregation: wave per 16-node bin, private 4 KB LDS accumulator,
// 8-deep unrolled gather for memory-level parallelism (no atomics) ----
template <bool FIRST>
__global__ __launch_bounds__(256) void agg_kernel(const float* __restrict__ h,
                                                  const float* __restrict__ scale,
                                                  const float* __restrict__ shift,
                                                  const int* __restrict__ binBase,
                                                  const int2* __restrict__ edges,
                                                  float* __restrict__ agg) {
    __shared__ float accAll[4][BINSZ * 64];   // 16 KB / block
    const int w = threadIdx.x >> 6, lane = threadIdx.x & 63;
    const int bin = blockIdx.x * 4 + w;
    if (bin >= NBINS) return;             // whole-wave exit; no __syncthreads below
    float* acc = accAll[w];
#pragma unroll
    for (int r = 0; r < BINSZ; ++r) acc[r * 64 + lane] = 0.f;
    const float sc = FIRST ? 1.f : scale[lane];
    const float sh = FIRST ? 0.f : shift[lane];
    const int beg = binBase[bin], end = binBase[bin + 1];
    for (int j = beg; j < end; j += 64) {
        const int n = min(64, end - j);
        int2 ed = (j + lane < end) ? edges[j + lane] : make_int2(0, 0);
        const int n8 = n & ~7;
        int t = 0;
        for (; t < n8; t += 8) {
            int   s_[8];
            float w_[8], h_[8];
#pragma unroll
            for (int u = 0; u < 8; ++u) {
                s_[u] = __shfl(ed.x, t + u);
                w_[u] = __int_as_float(__shfl(ed.y, t + u));
            }
#pragma unroll
            for (int u = 0; u < 8; ++u) h_[u] = h[(s_[u] >> 4) * 64 + lane];
#pragma unroll
            for (int u = 0; u < 8; ++u) {
                float hv = FIRST ? h_[u] : fmaf(h_[u], sc, sh);
                acc[(s_[u] & 15) * 64 + lane] += w_[u] * hv;
            }
        }
        for (; t < n; ++t) {
            const int sd = __shfl(ed.x, t);
            const float wt = __int_as_float(__shfl(ed.y, t));
            float hv = h[(sd >> 4) * 64 + lane];
            if (!FIRST) hv = fmaf(hv, sc, sh);
            acc[(sd & 15) * 64 + lane] += wt * hv;
        }
    }
    const int nodeBase = bin * BINSZ;
#pragma unroll
    for (int r = 0; r < BINSZ; ++r)
        agg[(nodeBase + r) * 64 + lane] = acc[r * 64 + lane];
}

// ---- y = PReLU(agg @ W^T + bias): block = 64-row tile, wave w = cols 16w..16w+15.
// 4x the wave count of the old thread-per-row kernel; same-row reuse via L1. ----
__global__ __launch_bounds__(256) void gemm_kernel(const float* __restrict__ agg,
                                                   const float* __restrict__ W,
                                                   const float* __restrict__ bias,
                                                   const float* __restrict__ pa_ptr,
                                                   float* __restrict__ y) {
    __shared__ float tile[4][64 * 17];
    const int wv = threadIdx.x >> 6, lane = threadIdx.x & 63;
    const int base = blockIdx.x * 64;
    const int row = base + lane;
    const float pa = *pa_ptr;
    float a[64];
    if (row < NNODES) {
        const float4* ap = (const float4*)(agg + row * 64);
#pragma unroll
        for (int i = 0; i < 16; ++i) {
            float4 t = ap[i];
            a[4 * i] = t.x; a[4 * i + 1] = t.y; a[4 * i + 2] = t.z; a[4 * i + 3] = t.w;
        }
    } else {
#pragma unroll
        for (int i = 0; i < 64; ++i) a[i] = 0.f;
    }
    float* tl = tile[wv];
#pragma unroll
    for (int ci = 0; ci < 16; ++ci) {
        const int c = wv * 16 + ci;       // wave-uniform
        const float* wr = W + c * 64;
        float acc = bias[c];
#pragma unroll
        for (int k = 0; k < 64; k += 4) {
            const float4 w4 = *(const float4*)(wr + k);
            acc += a[k] * w4.x + a[k + 1] * w4.y + a[k + 2] * w4.z + a[k + 3] * w4.w;
        }
        const float v = (acc >= 0.f) ? acc : pa * acc;
        tl[lane * 17 + ci] = v;
    }
    // wave-synchronous transpose staging -> semi-coalesced stores
#pragma unroll
    for (int s = 0; s < 16; ++s) {
        const int idx = s * 64 + lane;
        const int rr = idx >> 4, cl = idx & 15;
        const int grow = base + rr;
        if (grow < NNODES) y[grow * 64 + wv * 16 + cl] = tl[rr * 17 + cl];
    }
}

// ---- block-per-graph: per-graph sum + per-channel BN partials (no atomics) ----
__global__ __launch_bounds__(512) void stats_kernel(const float* __restrict__ y,
                                                    const int* __restrict__ endv,
                                                    float* __restrict__ gsum,
                                                    float* __restrict__ pS,
                                                    float* __restrict__ pQ) {
    __shared__ float red[3][8][64];
    const int g = blockIdx.x;
    const int w = threadIdx.x >> 6, lane = threadIdx.x & 63;
    const int r0 = (g == 0) ? 0 : endv[g - 1];
    const int r1 = endv[g];
    float ga = 0.f, ls = 0.f, lsq = 0.f;
    for (int r = r0 + w; r < r1; r += 8) {
        const float v = y[r * 64 + lane];
        ga += v; ls += v; lsq = fmaf(v, v, lsq);
    }
    red[0][w][lane] = ga; red[1][w][lane] = ls; red[2][w][lane] = lsq;
    __syncthreads();
    if (w == 0) {
        float a = 0.f, b = 0.f, c = 0.f;
#pragma unroll
        for (int k = 0; k < 8; ++k) {
            a += red[0][k][lane]; b += red[1][k][lane]; c += red[2][k][lane];
        }
        gsum[g * 64 + lane] = a;
        pS[g * 64 + lane] = b;
        pQ[g * 64 + lane] = c;
    }
}

// ---- single block: BN closure + pooled outputs straight into d_out ----
__global__ __launch_bounds__(1024) void finalize_kernel(const float* __restrict__ gsum,
                                                        const float* __restrict__ pS,
                                                        const float* __restrict__ pQ,
                                                        const int* __restrict__ endv,
                                                        const float* __restrict__ bn_w,
                                                        const float* __restrict__ bn_b,
                                                        float* __restrict__ scale,
                                                        float* __restrict__ shift,
                                                        float* __restrict__ out, int layer) {
    __shared__ float ssc[64], ssh[64];
    const int tid = threadIdx.x;
    if (tid < 64) {
        float s = 0.f, q = 0.f;
        for (int g = 0; g < NGRAPHS; ++g) {
            s += pS[g * 64 + tid];
            q += pQ[g * 64 + tid];
        }
        const float mean = s * (1.f / NNODES);
        const float var = fmaxf(q * (1.f / NNODES) - mean * mean, 0.f);
        const float inv = rsqrtf(var + BN_EPS);
        const float sc = inv * bn_w[tid];
        const float sh = bn_b[tid] - mean * sc;
        ssc[tid] = sc; ssh[tid] = sh;
        scale[tid] = sc; shift[tid] = sh;
    }
    __syncthreads();
    for (int idx = tid; idx < NGRAPHS * 64; idx += 1024) {
        const int g = idx >> 6, c = idx & 63;
        const int cnt = endv[g] - ((g == 0) ? 0 : endv[g - 1]);
        const float pooled = gsum[idx] * ssc[c] + (float)cnt * ssh[c];
        out[g * (NLAYERS * 64) + layer * 64 + c] = pooled;
        if (layer == NLAYERS - 1) out[NGRAPHS * NLAYERS * 64 + idx] = pooled;
    }
}

extern "C" void kernel_launch(void* const* d_in, const int* in_sizes, int n_in,
                              void* d_out, int out_size, void* d_ws, size_t ws_size,
                              hipStream_t stream) {
    const float* x     = (const float*)d_in[0];
    const int*   ei    = (const int*)d_in[1];
    const float* ea    = (const float*)d_in[2];
    const int*   batch = (const int*)d_in[3];
    const float* W     = (const float*)d_in[4];
    const float* b     = (const float*)d_in[5];
    const float* pa    = (const float*)d_in[6];
    const float* bn_w  = (const float*)d_in[7];
    const float* bn_b  = (const float*)d_in[8];
    float* out = (float*)d_out;
    float* ws  = (float*)d_ws;
    int*   wsi = (int*)d_ws;

    int2*  edges   = (int2*)(wsi + OFF_EDGES);
    int*   binBase = wsi + OFF_BINBASE;
    float* agg     = ws + OFF_AGG;
    float* y       = ws + OFF_Y;
    int*   counts  = wsi + OFF_COUNTS;
    int*   offs    = wsi + OFF_OFFS;
    int*   btot    = wsi + OFF_BTOT;
    float* scaleA  = ws + OFF_SCALE;
    float* shiftA  = ws + OFF_SHIFT;
    float* gsum    = ws + OFF_GSUM;
    float* pS      = ws + OFF_PS;
    float* pQ      = ws + OFF_PQ;
    int*   endv    = wsi + OFF_END;

    count_kernel<<<GBLK, 1024, 0, stream>>>(ei, counts);
    s1_kernel<<<(NBINS + 3) / 4, 256, 0, stream>>>(counts, offs, btot);
    s2_kernel<<<1, 1024, 0, stream>>>(btot, binBase);
    scatter_kernel<<<GBLK, 1024, 0, stream>>>(ei, ea, binBase, offs, edges);
    bounds_kernel<<<(NNODES + 1023) / 1024, 1024, 0, stream>>>(batch, endv);

    for (int l = 0; l < NLAYERS; ++l) {
        if (l == 0)
            agg_kernel<true><<<(NBINS + 3) / 4, 256, 0, stream>>>(x, nullptr, nullptr,
                                                                  binBase, edges, agg);
        else
            agg_kernel<false><<<(NBINS + 3) / 4, 256, 0, stream>>>(y, scaleA + (l - 1) * 64,
                                                                   shiftA + (l - 1) * 64,
                                                                   binBase, edges, agg);
        gemm_kernel<<<(NNODES + 63) / 64, 256, 0, stream>>>(agg, W + l * 4096, b + l * 64, pa, y);
        stats_kernel<<<NGRAPHS, 512, 0, stream>>>(y, endv, gsum, pS, pQ);
        finalize_kernel<<<1, 1024, 0, stream>>>(gsum, pS, pQ, endv, bn_w + l * 64,
                                                bn_b + l * 64, scaleA + l * 64,
                                                shiftA + l * 64, out, l);
    }
}

// Round 6
// 392.440 us; speedup vs baseline: 1.2965x; 1.2965x over previous
//
#include <hip/hip_runtime.h>

#define NNODES 100000
#define NEDGES 1000000
#define DIM 64
#define NGRAPHS 128
#define NLAYERS 3
#define BN_EPS 1e-5f

#define BINSZ 16
#define NBINS 6250          // 16 nodes per bin, 6250*16 == NNODES exactly
#define GBLK 256            // blocks for count/scatter passes
#define ECHUNK 3907         // ceil(NEDGES/GBLK)
#define SLICES 4            // row-slices per graph in stats

// workspace layout (4-byte element offsets)
#define OFF_EDGES   0            // int2[NEDGES] = 2,000,000 ints
#define OFF_BINBASE 2000000      // int[NBINS+1]
#define OFF_AGG     2006272      // float[NNODES*64]
#define OFF_Y       8406272      // float[NNODES*64]
// counts/offsets/binTotal overlay the (not yet used) Y region during preprocessing
#define OFF_COUNTS  8406272      // int[NBINS*GBLK] = 1,600,000
#define OFF_OFFS    10006272     // int[NBINS*GBLK] = 1,600,000
#define OFF_BTOT    11606272     // int[NBINS]
// stats partials overlay the AGG region (agg is dead between gemm and the next agg_kernel)
#define OFF_GSUM4   2006272      // float[NGRAPHS*SLICES*64] = 32768
#define OFF_PS4     2039040      // float[32768]
#define OFF_PQ4     2071808      // float[32768]
// persistent small stats region
#define OFF_SCALE   14806272     // float[NLAYERS*64]
#define OFF_SHIFT   14806464     // float[NLAYERS*64]
#define OFF_END     14806656     // int[NGRAPHS]

// ---- preprocessing: bin 1M edges by dst/16 with zero global atomics ----

__global__ __launch_bounds__(1024) void count_kernel(const int* __restrict__ ei,
                                                     int* __restrict__ counts) {
    __shared__ int hist[NBINS];
    const int tid = threadIdx.x, blk = blockIdx.x;
    for (int i = tid; i < NBINS; i += 1024) hist[i] = 0;
    __syncthreads();
    const int e0 = blk * ECHUNK, e1 = min(NEDGES, e0 + ECHUNK);
    for (int e = e0 + tid; e < e1; e += 1024)
        atomicAdd(&hist[ei[NEDGES + e] / BINSZ], 1);
    __syncthreads();
    for (int bin = tid; bin < NBINS; bin += 1024)
        counts[bin * GBLK + blk] = hist[bin];
}

// one wave per bin: exclusive scan of the GBLK per-block counts + bin total
__global__ __launch_bounds__(256) void s1_kernel(const int* __restrict__ counts,
                                                 int* __restrict__ offs,
                                                 int* __restrict__ btot) {
    const int bin = blockIdx.x * 4 + (threadIdx.x >> 6);
    const int lane = threadIdx.x & 63;
    if (bin >= NBINS) return;
    int carry = 0;
    for (int q = 0; q < GBLK; q += 64) {
        const int v = counts[bin * GBLK + q + lane];
        int s = v;
        for (int off = 1; off < 64; off <<= 1) {
            int t = __shfl_up(s, off);
            if (lane >= off) s += t;
        }
        offs[bin * GBLK + q + lane] = carry + s - v;
        carry += __shfl(s, 63);
    }
    if (lane == 0) btot[bin] = carry;
}

// single-block exclusive scan over NBINS bin totals -> binBase (+ sentinel)
__global__ __launch_bounds__(1024) void s2_kernel(const int* __restrict__ btot,
                                                  int* __restrict__ binBase) {
    __shared__ int s[1024];
    const int t = threadIdx.x;
    int running = 0;
    for (int base = 0; base < NBINS; base += 1024) {
        const int i = base + t;
        const int v = (i < NBINS) ? btot[i] : 0;
        __syncthreads();
        s[t] = v;
        __syncthreads();
        for (int off = 1; off < 1024; off <<= 1) {
            int x = (t >= off) ? s[t - off] : 0;
            __syncthreads();
            s[t] += x;
            __syncthreads();
        }
        if (i < NBINS) binBase[i] = running + s[t] - v;
        running += s[1023];
    }
    if (t == 0) binBase[NBINS] = running;
}

__global__ __launch_bounds__(1024) void scatter_kernel(const int* __restrict__ ei,
                                                       const float* __restrict__ ea,
                                                       const int* __restrict__ binBase,
                                                       const int* __restrict__ offs,
                                                       int2* __restrict__ edges) {
    __shared__ int cur[NBINS];
    const int tid = threadIdx.x, blk = blockIdx.x;
    for (int i = tid; i < NBINS; i += 1024)
        cur[i] = binBase[i] + offs[i * GBLK + blk];
    __syncthreads();
    const int e0 = blk * ECHUNK, e1 = min(NEDGES, e0 + ECHUNK);
    for (int e = e0 + tid; e < e1; e += 1024) {
        const int dst = ei[NEDGES + e];
        const int src = ei[e];
        const float w = ea[e];
        const int pos = atomicAdd(&cur[dst / BINSZ], 1);   // LDS atomic
        edges[pos] = make_int2((src << 4) | (dst & (BINSZ - 1)), __float_as_int(w));
    }
}

// per-graph end offsets from the sorted batch vector (no atomics)
__global__ __launch_bounds__(1024) void bounds_kernel(const int* __restrict__ batch,
                                                      int* __restrict__ endv) {
    const int i = blockIdx.x * 1024 + threadIdx.x;
    if (i >= NNODES) return;
    const int b0 = batch[i];
    const int b1 = (i + 1 < NNODES) ? batch[i + 1] : NGRAPHS;
    for (int g = b0; g < b1; ++g) endv[g] = i + 1;
    if (i == 0)
        for (int g = 0; g < b0; ++g) endv[g] = 0;
}

// ---- aggregation: wave per 16-node bin, private 4 KB LDS accumulator,
// 8-deep unrolled gather for memory-level parallelism (no atomics) ----
template <bool FIRST>
__global__ __launch_bounds__(256) void agg_kernel(const float* __restrict__ h,
                                                  const float* __restrict__ scale,
                                                  const float* __restrict__ shift,
                                                  const int* __restrict__ binBase,
                                                  const int2* __restrict__ edges,
                                                  float* __restrict__ agg) {
    __shared__ float accAll[4][BINSZ * 64];   // 16 KB / block
    const int w = threadIdx.x >> 6, lane = threadIdx.x & 63;
    const int bin = blockIdx.x * 4 + w;
    if (bin >= NBINS) return;             // whole-wave exit; no __syncthreads below
    float* acc = accAll[w];
#pragma unroll
    for (int r = 0; r < BINSZ; ++r) acc[r * 64 + lane] = 0.f;
    const float sc = FIRST ? 1.f : scale[lane];
    const float sh = FIRST ? 0.f : shift[lane];
    const int beg = binBase[bin], end = binBase[bin + 1];
    for (int j = beg; j < end; j += 64) {
        const int n = min(64, end - j);
        int2 ed = (j + lane < end) ? edges[j + lane] : make_int2(0, 0);
        const int n8 = n & ~7;
        int t = 0;
        for (; t < n8; t += 8) {
            int   s_[8];
            float w_[8], h_[8];
#pragma unroll
            for (int u = 0; u < 8; ++u) {
                s_[u] = __shfl(ed.x, t + u);
                w_[u] = __int_as_float(__shfl(ed.y, t + u));
            }
#pragma unroll
            for (int u = 0; u < 8; ++u) h_[u] = h[(s_[u] >> 4) * 64 + lane];
#pragma unroll
            for (int u = 0; u < 8; ++u) {
                float hv = FIRST ? h_[u] : fmaf(h_[u], sc, sh);
                acc[(s_[u] & 15) * 64 + lane] += w_[u] * hv;
            }
        }
        for (; t < n; ++t) {
            const int sd = __shfl(ed.x, t);
            const float wt = __int_as_float(__shfl(ed.y, t));
            float hv = h[(sd >> 4) * 64 + lane];
            if (!FIRST) hv = fmaf(hv, sc, sh);
            acc[(sd & 15) * 64 + lane] += wt * hv;
        }
    }
    const int nodeBase = bin * BINSZ;
#pragma unroll
    for (int r = 0; r < BINSZ; ++r)
        agg[(nodeBase + r) * 64 + lane] = acc[r * 64 + lane];
}

// ---- y = PReLU(agg @ W^T + bias): LDS-tiled SGEMM.
// block = 128 rows x 64 cols, 256 threads; thread = 4 rows (stride 32) x 8 cols,
// 32 independent accumulators (no serial chains). A[128][68] + Wt[64][68] in LDS
// (pad 68: A-reads conflict-free, W-reads 2-way=free, all 16B-aligned). ----
__global__ __launch_bounds__(256) void gemm_kernel(const float* __restrict__ agg,
                                                   const float* __restrict__ W,
                                                   const float* __restrict__ bias,
                                                   const float* __restrict__ pa_ptr,
                                                   float* __restrict__ y) {
    __shared__ float As[128 * 68];   // 34816 B
    __shared__ float Wt[64 * 68];    // 17408 B
    const int tid = threadIdx.x;
    const int base = blockIdx.x * 128;
    // stage A-tile (coalesced 1KB/wave loads, float4 LDS writes)
    for (int i = tid; i < 2048; i += 256) {
        const int r = i >> 4;
        const int q = (i & 15) * 4;
        const int row = base + r;
        float4 v = make_float4(0.f, 0.f, 0.f, 0.f);
        if (row < NNODES) v = *(const float4*)(agg + (size_t)row * 64 + q);
        *(float4*)&As[r * 68 + q] = v;
    }
    // stage W transposed: Wt[k][c] = W[c*64+k]
    for (int i = tid; i < 4096; i += 256)
        Wt[(i & 63) * 68 + (i >> 6)] = W[i];
    __syncthreads();

    const int tc = tid & 7;          // 8 col-groups of 8
    const int tr = tid >> 3;         // 32 row-groups of 4 (stride 32)
    float acc[4][8];
#pragma unroll
    for (int j = 0; j < 4; ++j)
#pragma unroll
        for (int c = 0; c < 8; ++c) acc[j][c] = 0.f;

    for (int kc = 0; kc < 16; ++kc) {
        const int k0 = kc * 4;
        float Af[4][4];
#pragma unroll
        for (int j = 0; j < 4; ++j) {
            const float4 t = *(const float4*)&As[(tr + 32 * j) * 68 + k0];
            Af[j][0] = t.x; Af[j][1] = t.y; Af[j][2] = t.z; Af[j][3] = t.w;
        }
#pragma unroll
        for (int kk = 0; kk < 4; ++kk) {
            const float4 w0 = *(const float4*)&Wt[(k0 + kk) * 68 + tc * 8];
            const float4 w1 = *(const float4*)&Wt[(k0 + kk) * 68 + tc * 8 + 4];
#pragma unroll
            for (int j = 0; j < 4; ++j) {
                const float a = Af[j][kk];
                acc[j][0] = fmaf(a, w0.x, acc[j][0]);
                acc[j][1] = fmaf(a, w0.y, acc[j][1]);
                acc[j][2] = fmaf(a, w0.z, acc[j][2]);
                acc[j][3] = fmaf(a, w0.w, acc[j][3]);
                acc[j][4] = fmaf(a, w1.x, acc[j][4]);
                acc[j][5] = fmaf(a, w1.y, acc[j][5]);
                acc[j][6] = fmaf(a, w1.z, acc[j][6]);
                acc[j][7] = fmaf(a, w1.w, acc[j][7]);
            }
        }
    }

    const float pa = *pa_ptr;
    const float4 b0 = *(const float4*)(bias + tc * 8);
    const float4 b1 = *(const float4*)(bias + tc * 8 + 4);
#pragma unroll
    for (int j = 0; j < 4; ++j) {
        const int row = base + tr + 32 * j;
        if (row >= NNODES) continue;
        float o[8];
        o[0] = acc[j][0] + b0.x; o[1] = acc[j][1] + b0.y;
        o[2] = acc[j][2] + b0.z; o[3] = acc[j][3] + b0.w;
        o[4] = acc[j][4] + b1.x; o[5] = acc[j][5] + b1.y;
        o[6] = acc[j][6] + b1.z; o[7] = acc[j][7] + b1.w;
#pragma unroll
        for (int c = 0; c < 8; ++c) o[c] = (o[c] >= 0.f) ? o[c] : pa * o[c];
        *(float4*)(y + (size_t)row * 64 + tc * 8)     = make_float4(o[0], o[1], o[2], o[3]);
        *(float4*)(y + (size_t)row * 64 + tc * 8 + 4) = make_float4(o[4], o[5], o[6], o[7]);
    }
}

// ---- block = (graph, slice): per-graph sum + per-channel BN partials (no atomics) ----
__global__ __launch_bounds__(256) void stats_kernel(const float* __restrict__ y,
                                                    const int* __restrict__ endv,
                                                    float* __restrict__ gsum4,
                                                    float* __restrict__ pS4,
                                                    float* __restrict__ pQ4) {
    __shared__ float red[3][4][64];
    const int g = blockIdx.x >> 2, s = blockIdx.x & 3;
    const int w = threadIdx.x >> 6, lane = threadIdx.x & 63;
    const int g0 = (g == 0) ? 0 : endv[g - 1];
    const int g1 = endv[g];
    const int len = g1 - g0;
    const int q0 = g0 + (len * s) / SLICES;
    const int q1 = g0 + (len * (s + 1)) / SLICES;
    float ga = 0.f, ls = 0.f, lsq = 0.f;
    for (int r = q0 + w; r < q1; r += 4) {
        const float v = y[r * 64 + lane];
        ga += v; ls += v; lsq = fmaf(v, v, lsq);
    }
    red[0][w][lane] = ga; red[1][w][lane] = ls; red[2][w][lane] = lsq;
    __syncthreads();
    if (w == 0) {
        float a = 0.f, b = 0.f, c = 0.f;
#pragma unroll
        for (int k = 0; k < 4; ++k) {
            a += red[0][k][lane]; b += red[1][k][lane]; c += red[2][k][lane];
        }
        gsum4[blockIdx.x * 64 + lane] = a;
        pS4[blockIdx.x * 64 + lane] = b;
        pQ4[blockIdx.x * 64 + lane] = c;
    }
}

// ---- single block: BN closure + pooled outputs straight into d_out ----
__global__ __launch_bounds__(512) void finalize_kernel(const float* __restrict__ gsum4,
                                                       const float* __restrict__ pS4,
                                                       const float* __restrict__ pQ4,
                                                       const int* __restrict__ endv,
                                                       const float* __restrict__ bn_w,
                                                       const float* __restrict__ bn_b,
                                                       float* __restrict__ scale,
                                                       float* __restrict__ shift,
                                                       float* __restrict__ out, int layer) {
    __shared__ float rS[8][64], rQ[8][64];
    __shared__ float ssc[64], ssh[64];
    const int tid = threadIdx.x;
    const int c = tid & 63, p = tid >> 6;    // p in 0..7
    float s = 0.f, q = 0.f;
    for (int sl = p; sl < NGRAPHS * SLICES; sl += 8) {
        s += pS4[sl * 64 + c];
        q += pQ4[sl * 64 + c];
    }
    rS[p][c] = s; rQ[p][c] = q;
    __syncthreads();
    if (tid < 64) {
        float S = 0.f, Q = 0.f;
#pragma unroll
        for (int k = 0; k < 8; ++k) { S += rS[k][c]; Q += rQ[k][c]; }
        const float mean = S * (1.f / NNODES);
        const float var = fmaxf(Q * (1.f / NNODES) - mean * mean, 0.f);
        const float inv = rsqrtf(var + BN_EPS);
        const float scv = inv * bn_w[c];
        const float shv = bn_b[c] - mean * scv;
        ssc[c] = scv; ssh[c] = shv;
        scale[c] = scv; shift[c] = shv;
    }
    __syncthreads();
    for (int idx = tid; idx < NGRAPHS * 64; idx += 512) {
        const int g = idx >> 6, ch = idx & 63;
        float gs = 0.f;
#pragma unroll
        for (int sl = 0; sl < SLICES; ++sl) gs += gsum4[(g * SLICES + sl) * 64 + ch];
        const int cnt = endv[g] - ((g == 0) ? 0 : endv[g - 1]);
        const float pooled = gs * ssc[ch] + (float)cnt * ssh[ch];
        out[g * (NLAYERS * 64) + layer * 64 + ch] = pooled;
        if (layer == NLAYERS - 1) out[NGRAPHS * NLAYERS * 64 + idx] = pooled;
    }
}

extern "C" void kernel_launch(void* const* d_in, const int* in_sizes, int n_in,
                              void* d_out, int out_size, void* d_ws, size_t ws_size,
                              hipStream_t stream) {
    const float* x     = (const float*)d_in[0];
    const int*   ei    = (const int*)d_in[1];
    const float* ea    = (const float*)d_in[2];
    const int*   batch = (const int*)d_in[3];
    const float* W     = (const float*)d_in[4];
    const float* b     = (const float*)d_in[5];
    const float* pa    = (const float*)d_in[6];
    const float* bn_w  = (const float*)d_in[7];
    const float* bn_b  = (const float*)d_in[8];
    float* out = (float*)d_out;
    float* ws  = (float*)d_ws;
    int*   wsi = (int*)d_ws;

    int2*  edges   = (int2*)(wsi + OFF_EDGES);
    int*   binBase = wsi + OFF_BINBASE;
    float* agg     = ws + OFF_AGG;
    float* y       = ws + OFF_Y;
    int*   counts  = wsi + OFF_COUNTS;
    int*   offs    = wsi + OFF_OFFS;
    int*   btot    = wsi + OFF_BTOT;
    float* gsum4   = ws + OFF_GSUM4;
    float* pS4     = ws + OFF_PS4;
    float* pQ4     = ws + OFF_PQ4;
    float* scaleA  = ws + OFF_SCALE;
    float* shiftA  = ws + OFF_SHIFT;
    int*   endv    = wsi + OFF_END;

    count_kernel<<<GBLK, 1024, 0, stream>>>(ei, counts);
    s1_kernel<<<(NBINS + 3) / 4, 256, 0, stream>>>(counts, offs, btot);
    s2_kernel<<<1, 1024, 0, stream>>>(btot, binBase);
    scatter_kernel<<<GBLK, 1024, 0, stream>>>(ei, ea, binBase, offs, edges);
    bounds_kernel<<<(NNODES + 1023) / 1024, 1024, 0, stream>>>(batch, endv);

    for (int l = 0; l < NLAYERS; ++l) {
        if (l == 0)
            agg_kernel<true><<<(NBINS + 3) / 4, 256, 0, stream>>>(x, nullptr, nullptr,
                                                                  binBase, edges, agg);
        else
            agg_kernel<false><<<(NBINS + 3) / 4, 256, 0, stream>>>(y, scaleA + (l - 1) * 64,
                                                                   shiftA + (l - 1) * 64,
                                                                   binBase, edges, agg);
        gemm_kernel<<<(NNODES + 127) / 128, 256, 0, stream>>>(agg, W + l * 4096, b + l * 64,
                                                              pa, y);
        stats_kernel<<<NGRAPHS * SLICES, 256, 0, stream>>>(y, endv, gsum4, pS4, pQ4);
        finalize_kernel<<<1, 512, 0, stream>>>(gsum4, pS4, pQ4, endv, bn_w + l * 64,
                                               bn_b + l * 64, scaleA + l * 64,
                                               shiftA + l * 64, out, l);
    }
}

// Round 7
// 342.749 us; speedup vs baseline: 1.4844x; 1.1450x over previous
//
#include <hip/hip_runtime.h>

#define NNODES 100000
#define NEDGES 1000000
#define DIM 64
#define NGRAPHS 128
#define NLAYERS 3
#define BN_EPS 1e-5f

#define BINSZ 8
#define NBINS 12500         // 8 nodes per bin, 12500*8 == NNODES exactly
#define GBLK 256            // blocks for count/scatter passes
#define ECHUNK 3907         // ceil(NEDGES/GBLK)
#define SLICES 4            // row-slices per graph in stats

// workspace layout (4-byte element offsets)
#define OFF_EDGES   0            // int2[NEDGES] = 2,000,000 ints
#define OFF_BINBASE 2000000      // int[NBINS+1]
#define OFF_AGG     2012544      // float[NNODES*64] = 6,400,000
#define OFF_YBF     8412544      // uint[NNODES*32] = 3,200,000 (bf16-packed y)
#define OFF_XBF     11612544     // uint[NNODES*32] = 3,200,000 (bf16-packed x)
// overlays (all strictly sequential in stream order):
#define OFF_COUNTS  OFF_YBF      // int[NBINS*GBLK] = 3,200,000; dead after s1
#define OFF_OFFS    OFF_XBF      // int[NBINS*GBLK] = 3,200,000; dead after scatter
#define OFF_BTOT    OFF_AGG      // int[NBINS]; dead after s2
#define OFF_GSUM4   (OFF_AGG + 16384)   // float[NGRAPHS*SLICES*64]; dead before next agg
#define OFF_PQ4     (OFF_AGG + 65536)   // float[NGRAPHS*SLICES*64]
// persistent small region
#define OFF_SCALE   14812544     // float[NLAYERS*64]
#define OFF_SHIFT   14812736     // float[NLAYERS*64]
#define OFF_END     14812928     // int[NGRAPHS]

__device__ __forceinline__ unsigned pack_bf16(float a, float b) {
    unsigned ua = __float_as_uint(a), ub = __float_as_uint(b);
    ua = (ua + 0x7FFFu + ((ua >> 16) & 1u)) >> 16;
    ub = (ub + 0x7FFFu + ((ub >> 16) & 1u)) & 0xFFFF0000u;
    return ua | ub;
}

// ---- preprocessing: bin 1M edges by dst/8 with zero global atomics ----

__global__ __launch_bounds__(1024) void count_kernel(const int* __restrict__ ei,
                                                     int* __restrict__ counts) {
    __shared__ int hist[NBINS];     // 50 KB
    const int tid = threadIdx.x, blk = blockIdx.x;
    for (int i = tid; i < NBINS; i += 1024) hist[i] = 0;
    __syncthreads();
    const int e0 = blk * ECHUNK, e1 = min(NEDGES, e0 + ECHUNK);
    for (int e = e0 + tid; e < e1; e += 1024)
        atomicAdd(&hist[ei[NEDGES + e] >> 3], 1);
    __syncthreads();
    for (int bin = tid; bin < NBINS; bin += 1024)
        counts[bin * GBLK + blk] = hist[bin];
}

// one wave per bin: exclusive scan of the GBLK per-block counts + bin total
__global__ __launch_bounds__(256) void s1_kernel(const int* __restrict__ counts,
                                                 int* __restrict__ offs,
                                                 int* __restrict__ btot) {
    const int bin = blockIdx.x * 4 + (threadIdx.x >> 6);
    const int lane = threadIdx.x & 63;
    if (bin >= NBINS) return;
    int carry = 0;
    for (int q = 0; q < GBLK; q += 64) {
        const int v = counts[bin * GBLK + q + lane];
        int s = v;
        for (int off = 1; off < 64; off <<= 1) {
            int t = __shfl_up(s, off);
            if (lane >= off) s += t;
        }
        offs[bin * GBLK + q + lane] = carry + s - v;
        carry += __shfl(s, 63);
    }
    if (lane == 0) btot[bin] = carry;
}

// single-block exclusive scan over NBINS bin totals -> binBase (+ sentinel);
// wave-shuffle scan + 16-wave LDS combine (2 barriers per 1024-chunk)
__global__ __launch_bounds__(1024) void s2_kernel(const int* __restrict__ btot,
                                                  int* __restrict__ binBase) {
    __shared__ int wsum[16];
    const int t = threadIdx.x, wid = t >> 6, lane = t & 63;
    int running = 0;
    for (int b = 0; b < NBINS; b += 1024) {
        const int i = b + t;
        const int v = (i < NBINS) ? btot[i] : 0;
        int s = v;
        for (int off = 1; off < 64; off <<= 1) {
            int x = __shfl_up(s, off);
            if (lane >= off) s += x;
        }
        __syncthreads();            // protect wsum from previous iteration
        if (lane == 63) wsum[wid] = s;
        __syncthreads();
        int pw = 0, tot = 0;
#pragma unroll
        for (int k = 0; k < 16; ++k) {
            const int x = wsum[k];
            tot += x;
            if (k < wid) pw += x;
        }
        if (i < NBINS) binBase[i] = running + pw + s - v;
        running += tot;
    }
    if (t == 0) binBase[NBINS] = running;
}

__global__ __launch_bounds__(1024) void scatter_kernel(const int* __restrict__ ei,
                                                       const float* __restrict__ ea,
                                                       const int* __restrict__ binBase,
                                                       const int* __restrict__ offs,
                                                       int2* __restrict__ edges) {
    __shared__ int cur[NBINS];      // 50 KB
    const int tid = threadIdx.x, blk = blockIdx.x;
    for (int i = tid; i < NBINS; i += 1024)
        cur[i] = binBase[i] + offs[i * GBLK + blk];
    __syncthreads();
    const int e0 = blk * ECHUNK, e1 = min(NEDGES, e0 + ECHUNK);
    for (int e = e0 + tid; e < e1; e += 1024) {
        const int dst = ei[NEDGES + e];
        const int src = ei[e];
        const float w = ea[e];
        const int pos = atomicAdd(&cur[dst >> 3], 1);   // LDS atomic
        edges[pos] = make_int2((src << 3) | (dst & (BINSZ - 1)), __float_as_int(w));
    }
}

// per-graph end offsets from the sorted batch vector (no atomics)
__global__ __launch_bounds__(1024) void bounds_kernel(const int* __restrict__ batch,
                                                      int* __restrict__ endv) {
    const int i = blockIdx.x * 1024 + threadIdx.x;
    if (i >= NNODES) return;
    const int b0 = batch[i];
    const int b1 = (i + 1 < NNODES) ? batch[i + 1] : NGRAPHS;
    for (int g = b0; g < b1; ++g) endv[g] = i + 1;
    if (i == 0)
        for (int g = 0; g < b0; ++g) endv[g] = 0;
}

// pack x to bf16 pairs: xbf[n*32+j] = (bf16(x[n][2j+1])<<16) | bf16(x[n][2j])
__global__ __launch_bounds__(256) void tobf_kernel(const float* __restrict__ x,
                                                   unsigned* __restrict__ xbf) {
    const int i = blockIdx.x * 256 + threadIdx.x;
    if (i >= NNODES * 32) return;
    const float2 v = *(const float2*)(x + (size_t)i * 2);
    xbf[i] = pack_bf16(v.x, v.y);
}

// ---- aggregation: wave per 8-node bin; 2 edges per wave-load (half-wave per row);
// per-half private LDS accumulators merged at the end (no atomics, no races) ----
template <bool FIRST>
__global__ __launch_bounds__(256) void agg_kernel(const unsigned* __restrict__ hbf,
                                                  const float* __restrict__ scale,
                                                  const float* __restrict__ shift,
                                                  const int* __restrict__ binBase,
                                                  const int2* __restrict__ edges,
                                                  float* __restrict__ agg) {
    __shared__ float accAll[4][2][BINSZ * 64];   // 16 KB / block
    const int w = threadIdx.x >> 6, lane = threadIdx.x & 63;
    const int bin = blockIdx.x * 4 + w;
    if (bin >= NBINS) return;            // whole-wave exit; no __syncthreads below
    const int half = lane >> 5, p = lane & 31, c0 = 2 * p;
    float* ac = accAll[w][half];
#pragma unroll
    for (int r = 0; r < BINSZ; ++r) *(float2*)&ac[r * 64 + c0] = make_float2(0.f, 0.f);
    float sc0 = 1.f, sc1 = 1.f, sh0 = 0.f, sh1 = 0.f;
    if (!FIRST) { sc0 = scale[c0]; sc1 = scale[c0 + 1]; sh0 = shift[c0]; sh1 = shift[c0 + 1]; }
    const int beg = binBase[bin], end = binBase[bin + 1];
    for (int j = beg; j < end; j += 64) {
        const int n = min(64, end - j);
        int2 ed = (j + lane < end) ? edges[j + lane] : make_int2(0, 0);
        const int n8 = n & ~7;
        int t = 0;
        for (; t < n8; t += 8) {       // 8 edges per iter (4 per half), 4 loads in flight
            int sd_[4]; float wt_[4]; unsigned u_[4];
#pragma unroll
            for (int q = 0; q < 4; ++q) {
                const int ii = t + 2 * q + half;
                sd_[q] = __shfl(ed.x, ii);
                wt_[q] = __int_as_float(__shfl(ed.y, ii));
            }
#pragma unroll
            for (int q = 0; q < 4; ++q) u_[q] = hbf[(size_t)(sd_[q] >> 3) * 32 + p];
#pragma unroll
            for (int q = 0; q < 4; ++q) {
                float h0 = __uint_as_float(u_[q] << 16);
                float h1 = __uint_as_float(u_[q] & 0xFFFF0000u);
                if (!FIRST) { h0 = fmaf(h0, sc0, sh0); h1 = fmaf(h1, sc1, sh1); }
                float2* a2 = (float2*)&ac[(sd_[q] & 7) * 64 + c0];
                float2 v = *a2;
                v.x = fmaf(wt_[q], h0, v.x);
                v.y = fmaf(wt_[q], h1, v.y);
                *a2 = v;
            }
        }
        for (; t < n; t += 2) {
            const int ii = min(t + half, n - 1);
            const int sd = __shfl(ed.x, ii);
            float wt = __int_as_float(__shfl(ed.y, ii));
            if (t + half >= n) wt = 0.f;
            const unsigned u = hbf[(size_t)(sd >> 3) * 32 + p];
            float h0 = __uint_as_float(u << 16);
            float h1 = __uint_as_float(u & 0xFFFF0000u);
            if (!FIRST) { h0 = fmaf(h0, sc0, sh0); h1 = fmaf(h1, sc1, sh1); }
            float2* a2 = (float2*)&ac[(sd & 7) * 64 + c0];
            float2 v = *a2;
            v.x = fmaf(wt, h0, v.x);
            v.y = fmaf(wt, h1, v.y);
            *a2 = v;
        }
    }
    const int nodeBase = bin * BINSZ;
#pragma unroll
    for (int r = 0; r < BINSZ; ++r)
        agg[(size_t)(nodeBase + r) * 64 + lane] =
            accAll[w][0][r * 64 + lane] + accAll[w][1][r * 64 + lane];
}

// ---- y = PReLU(agg @ W^T + bias) -> packed bf16. LDS-tiled SGEMM:
// block = 128 rows x 64 cols, thread = 4 rows (stride 32) x 8 cols. ----
__global__ __launch_bounds__(256) void gemm_kernel(const float* __restrict__ agg,
                                                   const float* __restrict__ W,
                                                   const float* __restrict__ bias,
                                                   const float* __restrict__ pa_ptr,
                                                   unsigned* __restrict__ ybf) {
    __shared__ float As[128 * 68];
    __shared__ float Wt[64 * 68];
    const int tid = threadIdx.x;
    const int base = blockIdx.x * 128;
    for (int i = tid; i < 2048; i += 256) {
        const int r = i >> 4;
        const int q = (i & 15) * 4;
        const int row = base + r;
        float4 v = make_float4(0.f, 0.f, 0.f, 0.f);
        if (row < NNODES) v = *(const float4*)(agg + (size_t)row * 64 + q);
        *(float4*)&As[r * 68 + q] = v;
    }
    for (int i = tid; i < 4096; i += 256)
        Wt[(i & 63) * 68 + (i >> 6)] = W[i];
    __syncthreads();

    const int tc = tid & 7;
    const int tr = tid >> 3;
    float acc[4][8];
#pragma unroll
    for (int j = 0; j < 4; ++j)
#pragma unroll
        for (int c = 0; c < 8; ++c) acc[j][c] = 0.f;

    for (int kc = 0; kc < 16; ++kc) {
        const int k0 = kc * 4;
        float Af[4][4];
#pragma unroll
        for (int j = 0; j < 4; ++j) {
            const float4 t = *(const float4*)&As[(tr + 32 * j) * 68 + k0];
            Af[j][0] = t.x; Af[j][1] = t.y; Af[j][2] = t.z; Af[j][3] = t.w;
        }
#pragma unroll
        for (int kk = 0; kk < 4; ++kk) {
            const float4 w0 = *(const float4*)&Wt[(k0 + kk) * 68 + tc * 8];
            const float4 w1 = *(const float4*)&Wt[(k0 + kk) * 68 + tc * 8 + 4];
#pragma unroll
            for (int j = 0; j < 4; ++j) {
                const float a = Af[j][kk];
                acc[j][0] = fmaf(a, w0.x, acc[j][0]);
                acc[j][1] = fmaf(a, w0.y, acc[j][1]);
                acc[j][2] = fmaf(a, w0.z, acc[j][2]);
                acc[j][3] = fmaf(a, w0.w, acc[j][3]);
                acc[j][4] = fmaf(a, w1.x, acc[j][4]);
                acc[j][5] = fmaf(a, w1.y, acc[j][5]);
                acc[j][6] = fmaf(a, w1.z, acc[j][6]);
                acc[j][7] = fmaf(a, w1.w, acc[j][7]);
            }
        }
    }

    const float pa = *pa_ptr;
    const float4 b0 = *(const float4*)(bias + tc * 8);
    const float4 b1 = *(const float4*)(bias + tc * 8 + 4);
#pragma unroll
    for (int j = 0; j < 4; ++j) {
        const int row = base + tr + 32 * j;
        if (row >= NNODES) continue;
        float o[8];
        o[0] = acc[j][0] + b0.x; o[1] = acc[j][1] + b0.y;
        o[2] = acc[j][2] + b0.z; o[3] = acc[j][3] + b0.w;
        o[4] = acc[j][4] + b1.x; o[5] = acc[j][5] + b1.y;
        o[6] = acc[j][6] + b1.z; o[7] = acc[j][7] + b1.w;
#pragma unroll
        for (int c = 0; c < 8; ++c) o[c] = (o[c] >= 0.f) ? o[c] : pa * o[c];
        uint4 pk;
        pk.x = pack_bf16(o[0], o[1]);
        pk.y = pack_bf16(o[2], o[3]);
        pk.z = pack_bf16(o[4], o[5]);
        pk.w = pack_bf16(o[6], o[7]);
        *(uint4*)(ybf + (size_t)row * 32 + tc * 4) = pk;
    }
}

// ---- block = (graph, slice): graph-sum + channel sumsq from packed y.
// graph-sum partials double as the BN channel-sum partials (same rows). ----
__global__ __launch_bounds__(256) void stats_kernel(const unsigned* __restrict__ ybf,
                                                    const int* __restrict__ endv,
                                                    float* __restrict__ gsum4,
                                                    float* __restrict__ pQ4) {
    __shared__ float red[2][8][64];
    const int g = blockIdx.x >> 2, s = blockIdx.x & 3;
    const int t = threadIdx.x, rl = t >> 5, p = t & 31, c0 = 2 * p;
    const int g0 = (g == 0) ? 0 : endv[g - 1];
    const int g1 = endv[g];
    const int len = g1 - g0;
    const int q0 = g0 + (len * s) / SLICES;
    const int q1 = g0 + (len * (s + 1)) / SLICES;
    float ga0 = 0.f, ga1 = 0.f, qq0 = 0.f, qq1 = 0.f;
    for (int r = q0 + rl; r < q1; r += 8) {
        const unsigned u = ybf[(size_t)r * 32 + p];
        const float f0 = __uint_as_float(u << 16);
        const float f1 = __uint_as_float(u & 0xFFFF0000u);
        ga0 += f0; ga1 += f1;
        qq0 = fmaf(f0, f0, qq0); qq1 = fmaf(f1, f1, qq1);
    }
    red[0][rl][c0] = ga0; red[0][rl][c0 + 1] = ga1;
    red[1][rl][c0] = qq0; red[1][rl][c0 + 1] = qq1;
    __syncthreads();
    if (rl == 0) {
        float a0 = 0.f, a1 = 0.f, b0 = 0.f, b1 = 0.f;
#pragma unroll
        for (int k = 0; k < 8; ++k) {
            a0 += red[0][k][c0]; a1 += red[0][k][c0 + 1];
            b0 += red[1][k][c0]; b1 += red[1][k][c0 + 1];
        }
        gsum4[blockIdx.x * 64 + c0] = a0; gsum4[blockIdx.x * 64 + c0 + 1] = a1;
        pQ4[blockIdx.x * 64 + c0] = b0;  pQ4[blockIdx.x * 64 + c0 + 1] = b1;
    }
}

// ---- single block: BN closure + pooled outputs straight into d_out ----
__global__ __launch_bounds__(512) void finalize_kernel(const float* __restrict__ gsum4,
                                                       const float* __restrict__ pQ4,
                                                       const int* __restrict__ endv,
                                                       const float* __restrict__ bn_w,
                                                       const float* __restrict__ bn_b,
                                                       float* __restrict__ scale,
                                                       float* __restrict__ shift,
                                                       float* __restrict__ out, int layer) {
    __shared__ float rS[8][64], rQ[8][64];
    __shared__ float ssc[64], ssh[64];
    const int tid = threadIdx.x;
    const int c = tid & 63, pp = tid >> 6;    // pp in 0..7
    float s = 0.f, q = 0.f;
    for (int sl = pp; sl < NGRAPHS * SLICES; sl += 8) {
        s += gsum4[sl * 64 + c];
        q += pQ4[sl * 64 + c];
    }
    rS[pp][c] = s; rQ[pp][c] = q;
    __syncthreads();
    if (tid < 64) {
        float S = 0.f, Q = 0.f;
#pragma unroll
        for (int k = 0; k < 8; ++k) { S += rS[k][c]; Q += rQ[k][c]; }
        const float mean = S * (1.f / NNODES);
        const float var = fmaxf(Q * (1.f / NNODES) - mean * mean, 0.f);
        const float inv = rsqrtf(var + BN_EPS);
        const float scv = inv * bn_w[c];
        const float shv = bn_b[c] - mean * scv;
        ssc[c] = scv; ssh[c] = shv;
        scale[c] = scv; shift[c] = shv;
    }
    __syncthreads();
    for (int idx = tid; idx < NGRAPHS * 64; idx += 512) {
        const int g = idx >> 6, ch = idx & 63;
        float gs = 0.f;
#pragma unroll
        for (int sl = 0; sl < SLICES; ++sl) gs += gsum4[(g * SLICES + sl) * 64 + ch];
        const int cnt = endv[g] - ((g == 0) ? 0 : endv[g - 1]);
        const float pooled = gs * ssc[ch] + (float)cnt * ssh[ch];
        out[g * (NLAYERS * 64) + layer * 64 + ch] = pooled;
        if (layer == NLAYERS - 1) out[NGRAPHS * NLAYERS * 64 + idx] = pooled;
    }
}

extern "C" void kernel_launch(void* const* d_in, const int* in_sizes, int n_in,
                              void* d_out, int out_size, void* d_ws, size_t ws_size,
                              hipStream_t stream) {
    const float* x     = (const float*)d_in[0];
    const int*   ei    = (const int*)d_in[1];
    const float* ea    = (const float*)d_in[2];
    const int*   batch = (const int*)d_in[3];
    const float* W     = (const float*)d_in[4];
    const float* b     = (const float*)d_in[5];
    const float* pa    = (const float*)d_in[6];
    const float* bn_w  = (const float*)d_in[7];
    const float* bn_b  = (const float*)d_in[8];
    float* out = (float*)d_out;
    float* ws  = (float*)d_ws;
    int*   wsi = (int*)d_ws;

    int2*     edges   = (int2*)(wsi + OFF_EDGES);
    int*      binBase = wsi + OFF_BINBASE;
    float*    agg     = ws + OFF_AGG;
    unsigned* ybf     = (unsigned*)(wsi + OFF_YBF);
    unsigned* xbf     = (unsigned*)(wsi + OFF_XBF);
    int*      counts  = wsi + OFF_COUNTS;
    int*      offs    = wsi + OFF_OFFS;
    int*      btot    = wsi + OFF_BTOT;
    float*    gsum4   = ws + OFF_GSUM4;
    float*    pQ4     = ws + OFF_PQ4;
    float*    scaleA  = ws + OFF_SCALE;
    float*    shiftA  = ws + OFF_SHIFT;
    int*      endv    = wsi + OFF_END;

    count_kernel<<<GBLK, 1024, 0, stream>>>(ei, counts);
    s1_kernel<<<(NBINS + 3) / 4, 256, 0, stream>>>(counts, offs, btot);
    s2_kernel<<<1, 1024, 0, stream>>>(btot, binBase);
    scatter_kernel<<<GBLK, 1024, 0, stream>>>(ei, ea, binBase, offs, edges);
    bounds_kernel<<<(NNODES + 1023) / 1024, 1024, 0, stream>>>(batch, endv);
    tobf_kernel<<<(NNODES * 32 + 255) / 256, 256, 0, stream>>>(x, xbf);

    for (int l = 0; l < NLAYERS; ++l) {
        if (l == 0)
            agg_kernel<true><<<(NBINS + 3) / 4, 256, 0, stream>>>(xbf, nullptr, nullptr,
                                                                  binBase, edges, agg);
        else
            agg_kernel<false><<<(NBINS + 3) / 4, 256, 0, stream>>>(ybf, scaleA + (l - 1) * 64,
                                                                   shiftA + (l - 1) * 64,
                                                                   binBase, edges, agg);
        gemm_kernel<<<(NNODES + 127) / 128, 256, 0, stream>>>(agg, W + l * 4096, b + l * 64,
                                                              pa, ybf);
        stats_kernel<<<NGRAPHS * SLICES, 256, 0, stream>>>(ybf, endv, gsum4, pQ4);
        finalize_kernel<<<1, 512, 0, stream>>>(gsum4, pQ4, endv, bn_w + l * 64,
                                               bn_b + l * 64, scaleA + l * 64,
                                               shiftA + l * 64, out, l);
    }
}

// Round 8
// 309.631 us; speedup vs baseline: 1.6432x; 1.1070x over previous
//
#include <hip/hip_runtime.h>

#define NNODES 100000
#define NEDGES 1000000
#define DIM 64
#define NGRAPHS 128
#define NLAYERS 3
#define BN_EPS 1e-5f

#define BINSZ 8
#define NBINS 12500         // 8 nodes per bin, 12500*8 == NNODES exactly
#define GBLK 256            // blocks/chunks for count/scatter passes
#define ECHUNK 3907         // ceil(NEDGES/GBLK)
#define SLICES 4            // row-slices per graph in stats

// workspace layout (4-byte element offsets, non-overlapping; ws >= 268 MB)
#define OFF_EDGES   0            // int2[NEDGES] = 2,000,000 ints
#define OFF_BINBASE 2000000      // int[NBINS+1]
#define OFF_AGG     2012544      // float[NNODES*64] = 6,400,000
#define OFF_YBF     8412544      // uint[NNODES*32] = 3,200,000 (bf16-packed y)
#define OFF_XBF     11612544     // uint[NNODES*32] = 3,200,000 (bf16-packed x)
#define OFF_CNT     14812544     // ushort[GBLK*NBINS] = 1,600,000 ints
#define OFF_OFS     16412544     // ushort[GBLK*NBINS] = 1,600,000 ints
#define OFF_BTOT    18012544     // int[NBINS]
#define OFF_GSUM4   18025088     // float[NGRAPHS*SLICES*64] = 32768
#define OFF_PQ4     18057856     // float[32768]
#define OFF_SCALE   18090624     // float[NLAYERS*64]
#define OFF_SHIFT   18090816     // float[NLAYERS*64]
#define OFF_END     18091008     // int[NGRAPHS]

__device__ __forceinline__ unsigned pack_bf16(float a, float b) {
    unsigned ua = __float_as_uint(a), ub = __float_as_uint(b);
    ua = (ua + 0x7FFFu + ((ua >> 16) & 1u)) >> 16;
    ub = (ub + 0x7FFFu + ((ub >> 16) & 1u)) & 0xFFFF0000u;
    return ua | ub;
}

// ---- pass 1: LDS histogram per edge-chunk -> counts[blk][bin] (ushort, contiguous);
// fused grid-stride epilogues: x -> packed bf16, per-graph bounds ----
__global__ __launch_bounds__(1024) void count_kernel(const int* __restrict__ ei,
                                                     const float* __restrict__ x,
                                                     const int* __restrict__ batch,
                                                     unsigned short* __restrict__ counts,
                                                     unsigned* __restrict__ xbf,
                                                     int* __restrict__ endv) {
    __shared__ int hist[NBINS];     // 50 KB
    const int tid = threadIdx.x, blk = blockIdx.x;
    for (int i = tid; i < NBINS; i += 1024) hist[i] = 0;
    __syncthreads();
    const int e0 = blk * ECHUNK, e1 = min(NEDGES, e0 + ECHUNK);
    for (int e = e0 + tid; e < e1; e += 1024)
        atomicAdd(&hist[ei[NEDGES + e] >> 3], 1);
    __syncthreads();
    unsigned short* crow = counts + (size_t)blk * NBINS;
    for (int bin = tid; bin < NBINS; bin += 1024)
        crow[bin] = (unsigned short)hist[bin];
    // fused: pack x to bf16 pairs
    const int gtid = blk * 1024 + tid;
    for (int i = gtid; i < NNODES * 32; i += GBLK * 1024) {
        const float2 v = *(const float2*)(x + (size_t)i * 2);
        xbf[i] = pack_bf16(v.x, v.y);
    }
    // fused: per-graph end offsets from sorted batch
    for (int i = gtid; i < NNODES; i += GBLK * 1024) {
        const int b0 = batch[i];
        const int b1 = (i + 1 < NNODES) ? batch[i + 1] : NGRAPHS;
        for (int g = b0; g < b1; ++g) endv[g] = i + 1;
        if (i == 0)
            for (int g = 0; g < b0; ++g) endv[g] = 0;
    }
}

// ---- pass 2: per-bin serial scan across the 256 chunk-counts (thread per bin,
// coalesced across lanes) -> offs[blk][bin] + bin totals ----
__global__ __launch_bounds__(256) void s1_kernel(const unsigned short* __restrict__ counts,
                                                 unsigned short* __restrict__ offs,
                                                 int* __restrict__ btot) {
    const int bin = blockIdx.x * 256 + threadIdx.x;
    if (bin >= NBINS) return;
    int run = 0;
    for (int blk = 0; blk < GBLK; ++blk) {
        const int v = counts[(size_t)blk * NBINS + bin];
        offs[(size_t)blk * NBINS + bin] = (unsigned short)run;
        run += v;
    }
    btot[bin] = run;
}

// ---- pass 3: single-block exclusive scan over bin totals -> binBase ----
__global__ __launch_bounds__(1024) void s2_kernel(const int* __restrict__ btot,
                                                  int* __restrict__ binBase) {
    __shared__ int wsum[16];
    const int t = threadIdx.x, wid = t >> 6, lane = t & 63;
    int running = 0;
    for (int b = 0; b < NBINS; b += 1024) {
        const int i = b + t;
        const int v = (i < NBINS) ? btot[i] : 0;
        int s = v;
        for (int off = 1; off < 64; off <<= 1) {
            int x = __shfl_up(s, off);
            if (lane >= off) s += x;
        }
        __syncthreads();
        if (lane == 63) wsum[wid] = s;
        __syncthreads();
        int pw = 0, tot = 0;
#pragma unroll
        for (int k = 0; k < 16; ++k) {
            const int x = wsum[k];
            tot += x;
            if (k < wid) pw += x;
        }
        if (i < NBINS) binBase[i] = running + pw + s - v;
        running += tot;
    }
    if (t == 0) binBase[NBINS] = running;
}

// ---- pass 4: scatter edges into bin-sorted order (LDS cursors, no global atomics) ----
__global__ __launch_bounds__(1024) void scatter_kernel(const int* __restrict__ ei,
                                                       const float* __restrict__ ea,
                                                       const int* __restrict__ binBase,
                                                       const unsigned short* __restrict__ offs,
                                                       int2* __restrict__ edges) {
    __shared__ int cur[NBINS];      // 50 KB
    const int tid = threadIdx.x, blk = blockIdx.x;
    const unsigned short* orow = offs + (size_t)blk * NBINS;
    for (int i = tid; i < NBINS; i += 1024)
        cur[i] = binBase[i] + (int)orow[i];
    __syncthreads();
    const int e0 = blk * ECHUNK, e1 = min(NEDGES, e0 + ECHUNK);
    for (int e = e0 + tid; e < e1; e += 1024) {
        const int dst = ei[NEDGES + e];
        const int src = ei[e];
        const float w = ea[e];
        const int pos = atomicAdd(&cur[dst >> 3], 1);   // LDS atomic
        edges[pos] = make_int2((src << 3) | (dst & (BINSZ - 1)), __float_as_int(w));
    }
}

// ---- aggregation: wave per 8-node bin; half-wave per bf16-packed row (2 edges per
// wave-load); 16-edge unroll = 8 gathers in flight per half; per-half private LDS
// accumulators merged at the end (no atomics, no races) ----
template <bool FIRST>
__global__ __launch_bounds__(256) void agg_kernel(const unsigned* __restrict__ hbf,
                                                  const float* __restrict__ scale,
                                                  const float* __restrict__ shift,
                                                  const int* __restrict__ binBase,
                                                  const int2* __restrict__ edges,
                                                  float* __restrict__ agg) {
    __shared__ float accAll[4][2][BINSZ * 64];   // 16 KB / block
    const int w = threadIdx.x >> 6, lane = threadIdx.x & 63;
    const int bin = blockIdx.x * 4 + w;          // grid*4 == NBINS exactly
    const int half = lane >> 5, p = lane & 31, c0 = 2 * p;
    float* ac = accAll[w][half];
#pragma unroll
    for (int r = 0; r < BINSZ; ++r) *(float2*)&ac[r * 64 + c0] = make_float2(0.f, 0.f);
    float sc0 = 1.f, sc1 = 1.f, sh0 = 0.f, sh1 = 0.f;
    if (!FIRST) { sc0 = scale[c0]; sc1 = scale[c0 + 1]; sh0 = shift[c0]; sh1 = shift[c0 + 1]; }
    const int beg = binBase[bin], end = binBase[bin + 1];
    for (int j = beg; j < end; j += 64) {
        const int n = min(64, end - j);
        int2 ed = (j + lane < end) ? edges[j + lane] : make_int2(0, 0);
        const int n16 = n & ~15;
        int t = 0;
        for (; t < n16; t += 16) {     // 16 edges per iter (8 per half), 8 loads in flight
            int sd_[8]; float wt_[8]; unsigned u_[8];
#pragma unroll
            for (int q = 0; q < 8; ++q) {
                const int ii = t + 2 * q + half;
                sd_[q] = __shfl(ed.x, ii);
                wt_[q] = __int_as_float(__shfl(ed.y, ii));
            }
#pragma unroll
            for (int q = 0; q < 8; ++q) u_[q] = hbf[(size_t)(sd_[q] >> 3) * 32 + p];
#pragma unroll
            for (int q = 0; q < 8; ++q) {
                float h0 = __uint_as_float(u_[q] << 16);
                float h1 = __uint_as_float(u_[q] & 0xFFFF0000u);
                if (!FIRST) { h0 = fmaf(h0, sc0, sh0); h1 = fmaf(h1, sc1, sh1); }
                float2* a2 = (float2*)&ac[(sd_[q] & 7) * 64 + c0];
                float2 v = *a2;
                v.x = fmaf(wt_[q], h0, v.x);
                v.y = fmaf(wt_[q], h1, v.y);
                *a2 = v;
            }
        }
        for (; t < n; t += 2) {
            const int ii = min(t + half, n - 1);
            const int sd = __shfl(ed.x, ii);
            float wt = __int_as_float(__shfl(ed.y, ii));
            if (t + half >= n) wt = 0.f;
            const unsigned u = hbf[(size_t)(sd >> 3) * 32 + p];
            float h0 = __uint_as_float(u << 16);
            float h1 = __uint_as_float(u & 0xFFFF0000u);
            if (!FIRST) { h0 = fmaf(h0, sc0, sh0); h1 = fmaf(h1, sc1, sh1); }
            float2* a2 = (float2*)&ac[(sd & 7) * 64 + c0];
            float2 v = *a2;
            v.x = fmaf(wt, h0, v.x);
            v.y = fmaf(wt, h1, v.y);
            *a2 = v;
        }
    }
    const int nodeBase = bin * BINSZ;
#pragma unroll
    for (int r = 0; r < BINSZ; ++r)
        agg[(size_t)(nodeBase + r) * 64 + lane] =
            accAll[w][0][r * 64 + lane] + accAll[w][1][r * 64 + lane];
}

// ---- y = PReLU(agg @ W^T + bias) -> packed bf16. LDS-tiled SGEMM:
// block = 128 rows x 64 cols, thread = 4 rows (stride 32) x 8 cols. ----
__global__ __launch_bounds__(256) void gemm_kernel(const float* __restrict__ agg,
                                                   const float* __restrict__ W,
                                                   const float* __restrict__ bias,
                                                   const float* __restrict__ pa_ptr,
                                                   unsigned* __restrict__ ybf) {
    __shared__ float As[128 * 68];
    __shared__ float Wt[64 * 68];
    const int tid = threadIdx.x;
    const int base = blockIdx.x * 128;
    for (int i = tid; i < 2048; i += 256) {
        const int r = i >> 4;
        const int q = (i & 15) * 4;
        const int row = base + r;
        float4 v = make_float4(0.f, 0.f, 0.f, 0.f);
        if (row < NNODES) v = *(const float4*)(agg + (size_t)row * 64 + q);
        *(float4*)&As[r * 68 + q] = v;
    }
    for (int i = tid; i < 4096; i += 256)
        Wt[(i & 63) * 68 + (i >> 6)] = W[i];
    __syncthreads();

    const int tc = tid & 7;
    const int tr = tid >> 3;
    float acc[4][8];
#pragma unroll
    for (int j = 0; j < 4; ++j)
#pragma unroll
        for (int c = 0; c < 8; ++c) acc[j][c] = 0.f;

    for (int kc = 0; kc < 16; ++kc) {
        const int k0 = kc * 4;
        float Af[4][4];
#pragma unroll
        for (int j = 0; j < 4; ++j) {
            const float4 t = *(const float4*)&As[(tr + 32 * j) * 68 + k0];
            Af[j][0] = t.x; Af[j][1] = t.y; Af[j][2] = t.z; Af[j][3] = t.w;
        }
#pragma unroll
        for (int kk = 0; kk < 4; ++kk) {
            const float4 w0 = *(const float4*)&Wt[(k0 + kk) * 68 + tc * 8];
            const float4 w1 = *(const float4*)&Wt[(k0 + kk) * 68 + tc * 8 + 4];
#pragma unroll
            for (int j = 0; j < 4; ++j) {
                const float a = Af[j][kk];
                acc[j][0] = fmaf(a, w0.x, acc[j][0]);
                acc[j][1] = fmaf(a, w0.y, acc[j][1]);
                acc[j][2] = fmaf(a, w0.z, acc[j][2]);
                acc[j][3] = fmaf(a, w0.w, acc[j][3]);
                acc[j][4] = fmaf(a, w1.x, acc[j][4]);
                acc[j][5] = fmaf(a, w1.y, acc[j][5]);
                acc[j][6] = fmaf(a, w1.z, acc[j][6]);
                acc[j][7] = fmaf(a, w1.w, acc[j][7]);
            }
        }
    }

    const float pa = *pa_ptr;
    const float4 b0 = *(const float4*)(bias + tc * 8);
    const float4 b1 = *(const float4*)(bias + tc * 8 + 4);
#pragma unroll
    for (int j = 0; j < 4; ++j) {
        const int row = base + tr + 32 * j;
        if (row >= NNODES) continue;
        float o[8];
        o[0] = acc[j][0] + b0.x; o[1] = acc[j][1] + b0.y;
        o[2] = acc[j][2] + b0.z; o[3] = acc[j][3] + b0.w;
        o[4] = acc[j][4] + b1.x; o[5] = acc[j][5] + b1.y;
        o[6] = acc[j][6] + b1.z; o[7] = acc[j][7] + b1.w;
#pragma unroll
        for (int c = 0; c < 8; ++c) o[c] = (o[c] >= 0.f) ? o[c] : pa * o[c];
        uint4 pk;
        pk.x = pack_bf16(o[0], o[1]);
        pk.y = pack_bf16(o[2], o[3]);
        pk.z = pack_bf16(o[4], o[5]);
        pk.w = pack_bf16(o[6], o[7]);
        *(uint4*)(ybf + (size_t)row * 32 + tc * 4) = pk;
    }
}

// ---- block = (graph, slice): graph-sum + channel sumsq from packed y.
// graph-sum partials double as BN channel-sum partials (same rows). ----
__global__ __launch_bounds__(256) void stats_kernel(const unsigned* __restrict__ ybf,
                                                    const int* __restrict__ endv,
                                                    float* __restrict__ gsum4,
                                                    float* __restrict__ pQ4) {
    __shared__ float red[2][8][64];
    const int g = blockIdx.x >> 2, s = blockIdx.x & 3;
    const int t = threadIdx.x, rl = t >> 5, p = t & 31, c0 = 2 * p;
    const int g0 = (g == 0) ? 0 : endv[g - 1];
    const int g1 = endv[g];
    const int len = g1 - g0;
    const int q0 = g0 + (len * s) / SLICES;
    const int q1 = g0 + (len * (s + 1)) / SLICES;
    float ga0 = 0.f, ga1 = 0.f, qq0 = 0.f, qq1 = 0.f;
    for (int r = q0 + rl; r < q1; r += 8) {
        const unsigned u = ybf[(size_t)r * 32 + p];
        const float f0 = __uint_as_float(u << 16);
        const float f1 = __uint_as_float(u & 0xFFFF0000u);
        ga0 += f0; ga1 += f1;
        qq0 = fmaf(f0, f0, qq0); qq1 = fmaf(f1, f1, qq1);
    }
    red[0][rl][c0] = ga0; red[0][rl][c0 + 1] = ga1;
    red[1][rl][c0] = qq0; red[1][rl][c0 + 1] = qq1;
    __syncthreads();
    if (rl == 0) {
        float a0 = 0.f, a1 = 0.f, b0 = 0.f, b1 = 0.f;
#pragma unroll
        for (int k = 0; k < 8; ++k) {
            a0 += red[0][k][c0]; a1 += red[0][k][c0 + 1];
            b0 += red[1][k][c0]; b1 += red[1][k][c0 + 1];
        }
        gsum4[blockIdx.x * 64 + c0] = a0; gsum4[blockIdx.x * 64 + c0 + 1] = a1;
        pQ4[blockIdx.x * 64 + c0] = b0;  pQ4[blockIdx.x * 64 + c0 + 1] = b1;
    }
}

// ---- single block: BN closure + pooled outputs straight into d_out ----
__global__ __launch_bounds__(512) void finalize_kernel(const float* __restrict__ gsum4,
                                                       const float* __restrict__ pQ4,
                                                       const int* __restrict__ endv,
                                                       const float* __restrict__ bn_w,
                                                       const float* __restrict__ bn_b,
                                                       float* __restrict__ scale,
                                                       float* __restrict__ shift,
                                                       float* __restrict__ out, int layer) {
    __shared__ float rS[8][64], rQ[8][64];
    __shared__ float ssc[64], ssh[64];
    const int tid = threadIdx.x;
    const int c = tid & 63, pp = tid >> 6;    // pp in 0..7
    float s = 0.f, q = 0.f;
    for (int sl = pp; sl < NGRAPHS * SLICES; sl += 8) {
        s += gsum4[sl * 64 + c];
        q += pQ4[sl * 64 + c];
    }
    rS[pp][c] = s; rQ[pp][c] = q;
    __syncthreads();
    if (tid < 64) {
        float S = 0.f, Q = 0.f;
#pragma unroll
        for (int k = 0; k < 8; ++k) { S += rS[k][c]; Q += rQ[k][c]; }
        const float mean = S * (1.f / NNODES);
        const float var = fmaxf(Q * (1.f / NNODES) - mean * mean, 0.f);
        const float inv = rsqrtf(var + BN_EPS);
        const float scv = inv * bn_w[c];
        const float shv = bn_b[c] - mean * scv;
        ssc[c] = scv; ssh[c] = shv;
        scale[c] = scv; shift[c] = shv;
    }
    __syncthreads();
    for (int idx = tid; idx < NGRAPHS * 64; idx += 512) {
        const int g = idx >> 6, ch = idx & 63;
        float gs = 0.f;
#pragma unroll
        for (int sl = 0; sl < SLICES; ++sl) gs += gsum4[(g * SLICES + sl) * 64 + ch];
        const int cnt = endv[g] - ((g == 0) ? 0 : endv[g - 1]);
        const float pooled = gs * ssc[ch] + (float)cnt * ssh[ch];
        out[g * (NLAYERS * 64) + layer * 64 + ch] = pooled;
        if (layer == NLAYERS - 1) out[NGRAPHS * NLAYERS * 64 + idx] = pooled;
    }
}

extern "C" void kernel_launch(void* const* d_in, const int* in_sizes, int n_in,
                              void* d_out, int out_size, void* d_ws, size_t ws_size,
                              hipStream_t stream) {
    const float* x     = (const float*)d_in[0];
    const int*   ei    = (const int*)d_in[1];
    const float* ea    = (const float*)d_in[2];
    const int*   batch = (const int*)d_in[3];
    const float* W     = (const float*)d_in[4];
    const float* b     = (const float*)d_in[5];
    const float* pa    = (const float*)d_in[6];
    const float* bn_w  = (const float*)d_in[7];
    const float* bn_b  = (const float*)d_in[8];
    float* out = (float*)d_out;
    float* ws  = (float*)d_ws;
    int*   wsi = (int*)d_ws;

    int2*           edges   = (int2*)(wsi + OFF_EDGES);
    int*            binBase = wsi + OFF_BINBASE;
    float*          agg     = ws + OFF_AGG;
    unsigned*       ybf     = (unsigned*)(wsi + OFF_YBF);
    unsigned*       xbf     = (unsigned*)(wsi + OFF_XBF);
    unsigned short* counts  = (unsigned short*)(wsi + OFF_CNT);
    unsigned short* offs    = (unsigned short*)(wsi + OFF_OFS);
    int*            btot    = wsi + OFF_BTOT;
    float*          gsum4   = ws + OFF_GSUM4;
    float*          pQ4     = ws + OFF_PQ4;
    float*          scaleA  = ws + OFF_SCALE;
    float*          shiftA  = ws + OFF_SHIFT;
    int*            endv    = wsi + OFF_END;

    count_kernel<<<GBLK, 1024, 0, stream>>>(ei, x, batch, counts, xbf, endv);
    s1_kernel<<<(NBINS + 255) / 256, 256, 0, stream>>>(counts, offs, btot);
    s2_kernel<<<1, 1024, 0, stream>>>(btot, binBase);
    scatter_kernel<<<GBLK, 1024, 0, stream>>>(ei, ea, binBase, offs, edges);

    for (int l = 0; l < NLAYERS; ++l) {
        if (l == 0)
            agg_kernel<true><<<NBINS / 4, 256, 0, stream>>>(xbf, nullptr, nullptr,
                                                            binBase, edges, agg);
        else
            agg_kernel<false><<<NBINS / 4, 256, 0, stream>>>(ybf, scaleA + (l - 1) * 64,
                                                             shiftA + (l - 1) * 64,
                                                             binBase, edges, agg);
        gemm_kernel<<<(NNODES + 127) / 128, 256, 0, stream>>>(agg, W + l * 4096, b + l * 64,
                                                              pa, ybf);
        stats_kernel<<<NGRAPHS * SLICES, 256, 0, stream>>>(ybf, endv, gsum4, pQ4);
        finalize_kernel<<<1, 512, 0, stream>>>(gsum4, pQ4, endv, bn_w + l * 64,
                                               bn_b + l * 64, scaleA + l * 64,
                                               shiftA + l * 64, out, l);
    }
}